// Round 6
// baseline (225.745 us; speedup 1.0000x reference)
//
#include <hip/hip_runtime.h>
#include <hip/hip_bf16.h>
#include <stdint.h>

#define B_N   16
#define C_N   256
#define W_N   64
#define HW_N  4096
#define CK_N  32      // f,g channels
#define CH_N  128     // h channels
#define HWP_N 1024    // pooled spatial
#define MR_N  192     // CK+CK+CH rows in fused conv weight

typedef __attribute__((ext_vector_type(8))) short short8;
typedef __attribute__((ext_vector_type(4))) short short4v;
typedef __attribute__((ext_vector_type(4))) float f32x4;

#define MFMA(a, b, c) __builtin_amdgcn_mfma_f32_16x16x32_bf16((a), (b), (c), 0, 0, 0)

// K=16 bf16 MFMA: A,B = 4 bf16 (2 VGPRs); C/D row=quad*4+r, col=l15
__device__ __forceinline__ f32x4 MFMA16B(short4v a, short4v b, f32x4 c) {
#if __has_builtin(__builtin_amdgcn_mfma_f32_16x16x16bf16_1k)
    return __builtin_amdgcn_mfma_f32_16x16x16bf16_1k(a, b, c, 0, 0, 0);
#else
    asm("v_mfma_f32_16x16x16_bf16 %0, %1, %2, %0" : "+v"(c) : "v"(a), "v"(b));
    return c;
#endif
}

__device__ __forceinline__ unsigned short f2bf(float f) {
    union { float f; unsigned u; } v; v.f = f;
    unsigned r = v.u + 0x7FFFu + ((v.u >> 16) & 1u);   // RNE
    return (unsigned short)(r >> 16);
}
// round-half-up bf16 pair pack: 3 VALU ops (add, add, v_perm)
__device__ __forceinline__ unsigned packrn(float lo, float hi) {
    unsigned a = __float_as_uint(lo) + 0x8000u;
    unsigned b = __float_as_uint(hi) + 0x8000u;
    return __builtin_amdgcn_perm(b, a, 0x07060302);  // (a>>16)|(b&0xFFFF0000)
}
__device__ __forceinline__ short8 ld8(const void* p) {
    return *reinterpret_cast<const short8*>(p);
}

// ---------------- kernel 0: cast weights to bf16 ----------------
__global__ __launch_bounds__(256) void k_prep(
    const float* __restrict__ wf, const float* __restrict__ wg,
    const float* __restrict__ wh, const float* __restrict__ wv,
    unsigned short* __restrict__ Wc, unsigned short* __restrict__ Wv)
{
    int i = blockIdx.x * 256 + threadIdx.x;
    if (i < MR_N * C_N) {
        int r = i / C_N, c = i % C_N;
        float v = (r < 32) ? wf[r * C_N + c]
                : (r < 64) ? wg[(r - 32) * C_N + c]
                           : wh[(r - 64) * C_N + c];
        Wc[i] = f2bf(v);
    }
    if (i < C_N * CH_N) Wv[i] = f2bf(wv[i]);
}

// ---------------- kernel 1: fused conv1x1 (f,g,h) + 2x2 maxpool ----------------
// f_/g_/h_ all bf16.
__global__ __launch_bounds__(256) void k_conv_fgh(
    const float* __restrict__ x, const unsigned short* __restrict__ Wc,
    const float* __restrict__ bfp, const float* __restrict__ bgp, const float* __restrict__ bhp,
    unsigned short* __restrict__ f_, unsigned short* __restrict__ g_, unsigned short* __restrict__ h_)
{
    __shared__ __align__(16) unsigned char lds[64 * 512];
    const int T = threadIdx.x;
    const int lane = T & 63, wid = T >> 6;
    const int blk = blockIdx.x;
    const int b = blk >> 6;
    const int seg = blk & 63;
    const int rp = seg >> 1;     // pooled row 0..31
    const int half = seg & 1;    // which 32-wide half of the row pair
    const float* xb = x + (size_t)b * C_N * HW_N;

    // stage x -> LDS bf16 (transpose to [px][ch] with chunk-XOR swizzle)
    #pragma unroll
    for (int i = 0; i < 8; ++i) {
        int task = i * 256 + T;        // 0..2047 = 16 px-quads x 128 ch-pairs
        int pq = task & 15;
        int cp = task >> 4;            // channel pair 0..127
        int px0 = pq * 4;
        int row = 2 * rp + (px0 >> 5);
        int wcol = half * 32 + (px0 & 31);
        const float4 v0 = *reinterpret_cast<const float4*>(xb + (size_t)(2 * cp) * HW_N + row * W_N + wcol);
        const float4 v1 = *reinterpret_cast<const float4*>(xb + (size_t)(2 * cp + 1) * HW_N + row * W_N + wcol);
        float vlo[4] = {v0.x, v0.y, v0.z, v0.w};
        float vhi[4] = {v1.x, v1.y, v1.z, v1.w};
        int kc = cp >> 2, co = cp & 3;
        #pragma unroll
        for (int j = 0; j < 4; ++j) {
            int px = px0 + j;
            *reinterpret_cast<unsigned*>(lds + px * 512 + ((kc ^ (px & 31)) << 4) + co * 4)
                = packrn(vlo[j], vhi[j]);
        }
    }
    __syncthreads();

    const int l15 = lane & 15, quad = lane >> 4;
    f32x4 acc[3][4];
    #pragma unroll
    for (int mt = 0; mt < 3; ++mt)
        #pragma unroll
        for (int nt = 0; nt < 4; ++nt)
            acc[mt][nt] = f32x4{0.f, 0.f, 0.f, 0.f};

    const int m0base = wid * 48;
    for (int k0 = 0; k0 < 256; k0 += 32) {
        short8 afr[3];
        #pragma unroll
        for (int mt = 0; mt < 3; ++mt)
            afr[mt] = ld8(Wc + (size_t)(m0base + mt * 16 + l15) * C_N + k0 + quad * 8);
        #pragma unroll
        for (int nt = 0; nt < 4; ++nt) {
            int px = nt * 16 + l15;
            int kc = (k0 >> 3) + quad;
            short8 bfr = ld8(lds + px * 512 + ((kc ^ (px & 31)) << 4));
            #pragma unroll
            for (int mt = 0; mt < 3; ++mt)
                acc[mt][nt] = MFMA(afr[mt], bfr, acc[mt][nt]);
        }
    }

    // epilogue: bias, pool, scatter to f/g/h
    #pragma unroll
    for (int mt = 0; mt < 3; ++mt) {
        int mbase = m0base + mt * 16;
        int mrow0 = mbase + quad * 4;
        float bias[4];
        #pragma unroll
        for (int r = 0; r < 4; ++r) {
            int m = mrow0 + r;
            bias[r] = (m < 32) ? bfp[m] : (m < 64) ? bgp[m - 32] : bhp[m - 64];
        }
        if (mbase < 32) {
            #pragma unroll
            for (int nt = 0; nt < 4; ++nt) {
                int px = nt * 16 + l15;
                int p = (2 * rp + (px >> 5)) * W_N + half * 32 + (px & 31);
                uint2 u;
                u.x = packrn(acc[mt][nt][0] + bias[0], acc[mt][nt][1] + bias[1]);
                u.y = packrn(acc[mt][nt][2] + bias[2], acc[mt][nt][3] + bias[3]);
                *reinterpret_cast<uint2*>(f_ + ((size_t)b * HW_N + p) * CK_N + mrow0) = u;
            }
        } else if (mbase < 64) {
            int gc0 = mrow0 - 32;
            #pragma unroll
            for (int nt = 0; nt < 2; ++nt) {
                float pv[4];
                #pragma unroll
                for (int r = 0; r < 4; ++r) {
                    float m1 = fmaxf(acc[mt][nt][r], acc[mt][nt + 2][r]);
                    pv[r] = fmaxf(m1, __shfl_xor(m1, 1)) + bias[r];
                }
                if ((lane & 1) == 0) {
                    int kp = rp * 32 + half * 16 + ((nt * 16 + l15) >> 1);
                    uint2 u;
                    u.x = packrn(pv[0], pv[1]);
                    u.y = packrn(pv[2], pv[3]);
                    *reinterpret_cast<uint2*>(g_ + ((size_t)b * HWP_N + kp) * CK_N + gc0) = u;
                }
            }
        } else {
            int hc0 = mrow0 - 64;
            #pragma unroll
            for (int nt = 0; nt < 2; ++nt) {
                float pv[4];
                #pragma unroll
                for (int r = 0; r < 4; ++r) {
                    float m1 = fmaxf(acc[mt][nt][r], acc[mt][nt + 2][r]);
                    pv[r] = fmaxf(m1, __shfl_xor(m1, 1)) + bias[r];
                }
                #pragma unroll
                for (int r = 0; r < 4; ++r) {
                    int lo = (int)(packrn(pv[r], pv[r]) & 0xFFFFu);  // bf16 bits
                    int hi = __shfl_down(lo, 2);
                    if ((lane & 3) == 0) {
                        int kp2 = rp * 32 + half * 16 + nt * 8 + (l15 >> 1);
                        *reinterpret_cast<unsigned*>(
                            h_ + ((size_t)b * CH_N + hc0 + r) * HWP_N + kp2)
                            = (unsigned)lo | ((unsigned)hi << 16);
                    }
                }
            }
        }
    }
}

// ---------------- kernel 2: fused attention ----------------
// Single pass, fixed logit shift (no row max): p = 2^(s*log2e - 28.854), P/V bf16
// (fp32-like exponent range makes the fixed shift safe). Intra-block key split:
// 4 waves = 2 query-groups x 2 key-halves; partials combined via block LDS.
// Grid 1024 (16 b x 64 qtiles of 64 queries) -> ~3 waves/SIMD.
__global__ __launch_bounds__(256, 3) void k_attn(
    const unsigned short* __restrict__ f_, const unsigned short* __restrict__ g_,
    const unsigned short* __restrict__ h_, unsigned short* __restrict__ o_)
{
    __shared__ __align__(16) unsigned char lds[2 * 17408];  // 2 V bufs; reused for combine
    const int T = threadIdx.x;
    const int lane = T & 63, wid = T >> 6;
    const int l15 = lane & 15, quad = lane >> 4;
    const int qw = wid & 1;          // query sub-tile
    const int kh = wid >> 1;         // key half

    const int blk = blockIdx.x;      // 1024 = 16 b x 64 qtiles
    const int b = blk >> 6;
    const int q0w = (blk & 63) * 64 + qw * 32;
    const unsigned short* fb = f_ + (size_t)b * HW_N * CK_N;
    const unsigned short* gb = g_ + ((size_t)b * HWP_N + kh * 512) * CK_N;
    unsigned char* Vw = lds + kh * 17408;

    // staging: pair = 128 threads sharing kh_t; thread covers 8 rows x 16 B
    const int tt = T & 127, kh_t = T >> 7;
    const int sch = tt >> 3, skq = tt & 7;
    const unsigned short* hs = h_ + (size_t)b * CH_N * HWP_N + kh_t * 512;
    unsigned char* Vs = lds + kh_t * 17408;

    short8 ffr[2];
    #pragma unroll
    for (int qt = 0; qt < 2; ++qt)
        ffr[qt] = ld8(fb + (size_t)(q0w + qt * 16 + l15) * CK_N + quad * 8);

    const f32x4 zf = {0.f, 0.f, 0.f, 0.f};
    f32x4 oacc[2][8];   // [qt][ct]; D row = ch(quad*4+r), col = query(l15)
    #pragma unroll
    for (int qt = 0; qt < 2; ++qt)
        #pragma unroll
        for (int ct = 0; ct < 8; ++ct)
            oacc[qt][ct] = f32x4{0.f, 0.f, 0.f, 0.f};
    float lsum[2] = {0.f, 0.f};

    // prefetch chunk 0
    uint4 vpre[8];
    #pragma unroll
    for (int i = 0; i < 8; ++i)
        vpre[i] = *reinterpret_cast<const uint4*>(hs + (size_t)(sch + i * 16) * HWP_N + skq * 8);
    short8 gcur[4];
    #pragma unroll
    for (int kt = 0; kt < 4; ++kt)
        gcur[kt] = ld8(gb + (size_t)(kt * 16 + l15) * CK_N + quad * 8);

    for (int c = 0; c < 8; ++c) {
        const int key0 = c * 64;
        __syncthreads();   // previous chunk's V reads done
        #pragma unroll
        for (int i = 0; i < 8; ++i) {
            unsigned char* dst = Vs + (sch + i * 16) * 136 + skq * 16;
            *reinterpret_cast<uint2*>(dst)     = uint2{vpre[i].x, vpre[i].y};
            *reinterpret_cast<uint2*>(dst + 8) = uint2{vpre[i].z, vpre[i].w};
        }
        if (c < 7) {
            #pragma unroll
            for (int i = 0; i < 8; ++i)
                vpre[i] = *reinterpret_cast<const uint4*>(
                    hs + (size_t)(sch + i * 16) * HWP_N + key0 + 64 + skq * 8);
        }
        __syncthreads();   // V writes visible

        // QK: sp row=key(quad*4+r), col=q(l15)
        f32x4 sp[2][4];
        #pragma unroll
        for (int kt = 0; kt < 4; ++kt) {
            sp[0][kt] = MFMA(gcur[kt], ffr[0], zf);
            sp[1][kt] = MFMA(gcur[kt], ffr[1], zf);
        }
        if (c < 7) {
            #pragma unroll
            for (int kt = 0; kt < 4; ++kt)
                gcur[kt] = ld8(gb + (size_t)(key0 + 64 + kt * 16 + l15) * CK_N + quad * 8);
        }

        // exp2 fixed shift, accumulate denom, build bf16 B-frags in regs
        short4v pf[2][4];
        #pragma unroll
        for (int qt = 0; qt < 2; ++qt) {
            float lw = 0.f;
            #pragma unroll
            for (int kt = 0; kt < 4; ++kt) {
                float p0 = __builtin_amdgcn_exp2f(sp[qt][kt][0] * 1.44269504f - 28.85390082f);
                float p1 = __builtin_amdgcn_exp2f(sp[qt][kt][1] * 1.44269504f - 28.85390082f);
                float p2 = __builtin_amdgcn_exp2f(sp[qt][kt][2] * 1.44269504f - 28.85390082f);
                float p3 = __builtin_amdgcn_exp2f(sp[qt][kt][3] * 1.44269504f - 28.85390082f);
                lw += (p0 + p1) + (p2 + p3);
                uint2 u{packrn(p0, p1), packrn(p2, p3)};
                pf[qt][kt] = __builtin_bit_cast(short4v, u);
            }
            lsum[qt] += lw;
        }

        // PV: A = V[ch][4 keys] (b64 LDS, conflict-free), B = pf (regs), K=16
        const int vbase = l15 * 136 + quad * 8;
        #pragma unroll
        for (int ct = 0; ct < 8; ++ct) {
            #pragma unroll
            for (int kt = 0; kt < 4; ++kt) {
                short4v afr = *reinterpret_cast<const short4v*>(Vw + vbase + ct * 2176 + kt * 32);
                oacc[0][ct] = MFMA16B(afr, pf[0][kt], oacc[0][ct]);
                oacc[1][ct] = MFMA16B(afr, pf[1][kt], oacc[1][ct]);
            }
        }
    }

    // reduce denominator across quads (lanes share query = l15)
    lsum[0] += __shfl_xor(lsum[0], 16); lsum[0] += __shfl_xor(lsum[0], 32);
    lsum[1] += __shfl_xor(lsum[1], 16); lsum[1] += __shfl_xor(lsum[1], 32);

    // combine key-halves through LDS (reuse V space)
    float* cmb = reinterpret_cast<float*>(lds);          // 32 slots x 1 KB
    float* cls = reinterpret_cast<float*>(lds + 32768);  // 2x2x64 f32
    __syncthreads();   // all PV reads done
    if (kh == 1) {
        #pragma unroll
        for (int qt = 0; qt < 2; ++qt) {
            #pragma unroll
            for (int ct = 0; ct < 8; ++ct)
                *reinterpret_cast<f32x4*>(cmb + ((qw * 16 + qt * 8 + ct) * 64 + lane) * 4)
                    = oacc[qt][ct];
            cls[(qw * 2 + qt) * 64 + lane] = lsum[qt];
        }
    }
    __syncthreads();
    if (kh == 0) {
        float rl[2];
        #pragma unroll
        for (int qt = 0; qt < 2; ++qt)
            rl[qt] = 1.f / (lsum[qt] + cls[(qw * 2 + qt) * 64 + lane]);
        unsigned short* ob = o_ + (size_t)b * HW_N * CH_N;
        #pragma unroll
        for (int qt = 0; qt < 2; ++qt) {
            int q = q0w + qt * 16 + l15;
            #pragma unroll
            for (int ct = 0; ct < 8; ++ct) {
                f32x4 s = oacc[qt][ct]
                    + *reinterpret_cast<const f32x4*>(cmb + ((qw * 16 + qt * 8 + ct) * 64 + lane) * 4);
                uint2 u;
                u.x = packrn(s[0] * rl[qt], s[1] * rl[qt]);
                u.y = packrn(s[2] * rl[qt], s[3] * rl[qt]);
                *reinterpret_cast<uint2*>(ob + (size_t)q * CH_N + ct * 16 + quad * 4) = u;
            }
        }
    }
}

// ---------------- kernel 3: final conv1x1 + gamma + residual ----------------
__global__ __launch_bounds__(256) void k_out(
    const unsigned short* __restrict__ o_, const unsigned short* __restrict__ Wv,
    const float* __restrict__ bv, const float* __restrict__ x,
    const float* __restrict__ gamma_p, float* __restrict__ out)
{
    __shared__ __align__(16) unsigned char lds[64 * 272];
    const int T = threadIdx.x;
    const int lane = T & 63, wid = T >> 6;
    const int blk = blockIdx.x;
    const int b = blk >> 6;
    const int p0 = (blk & 63) * 64;
    const unsigned short* ob = o_ + ((size_t)b * HW_N + p0) * CH_N;

    #pragma unroll
    for (int i = 0; i < 4; ++i) {      // stage o tile: 64px x 128ch, padded rows
        int task = i * 256 + T;
        int p = task >> 4, kc = task & 15;
        short8 v = ld8(ob + p * CH_N + kc * 8);
        *reinterpret_cast<short8*>(lds + p * 272 + kc * 16) = v;
    }
    __syncthreads();

    const int l15 = lane & 15, quad = lane >> 4;
    f32x4 acc[4][4];   // acc[oc-tile][px-tile]; D row=px(quad*4+r), col=oc(l15)
    #pragma unroll
    for (int mt = 0; mt < 4; ++mt)
        #pragma unroll
        for (int nt = 0; nt < 4; ++nt)
            acc[mt][nt] = f32x4{0.f, 0.f, 0.f, 0.f};

    const int m0b = wid * 64;
    #pragma unroll
    for (int k0 = 0; k0 < 128; k0 += 32) {
        short8 bfr[4];   // o-tile fragments, m = px (A operand)
        #pragma unroll
        for (int nt = 0; nt < 4; ++nt)
            bfr[nt] = ld8(lds + (nt * 16 + l15) * 272 + k0 * 2 + quad * 16);
        #pragma unroll
        for (int mt = 0; mt < 4; ++mt) {
            short8 afr = ld8(Wv + (size_t)(m0b + mt * 16 + l15) * CH_N + k0 + quad * 8);
            #pragma unroll
            for (int nt = 0; nt < 4; ++nt)
                acc[mt][nt] = MFMA(bfr[nt], afr, acc[mt][nt]);  // A=o(px), B=Wv(oc)
        }
    }

    const float gamma = *gamma_p;
    const float* xb = x + (size_t)b * C_N * HW_N;
    float* outb = out + (size_t)b * C_N * HW_N;
    #pragma unroll
    for (int mt = 0; mt < 4; ++mt) {
        int oc = m0b + mt * 16 + l15;
        float bvv = bv[oc];
        #pragma unroll
        for (int nt = 0; nt < 4; ++nt) {
            size_t base = (size_t)oc * HW_N + p0 + nt * 16 + quad * 4;
            float4 xv = *reinterpret_cast<const float4*>(xb + base);
            float4 ov;
            ov.x = gamma * (acc[mt][nt][0] + bvv) + xv.x;
            ov.y = gamma * (acc[mt][nt][1] + bvv) + xv.y;
            ov.z = gamma * (acc[mt][nt][2] + bvv) + xv.z;
            ov.w = gamma * (acc[mt][nt][3] + bvv) + xv.w;
            *reinterpret_cast<float4*>(outb + base) = ov;
        }
    }
}

// ---------------- launch ----------------
extern "C" void kernel_launch(void* const* d_in, const int* in_sizes, int n_in,
                              void* d_out, int out_size, void* d_ws, size_t ws_size,
                              hipStream_t stream) {
    const float* x     = (const float*)d_in[0];
    const float* wf    = (const float*)d_in[1];
    const float* bf    = (const float*)d_in[2];
    const float* wg    = (const float*)d_in[3];
    const float* bg    = (const float*)d_in[4];
    const float* wh    = (const float*)d_in[5];
    const float* bh    = (const float*)d_in[6];
    const float* wv    = (const float*)d_in[7];
    const float* bv    = (const float*)d_in[8];
    const float* gamma = (const float*)d_in[9];
    float* out = (float*)d_out;
    char* ws = (char*)d_ws;

    unsigned short* f_ = (unsigned short*)(ws);                 //  4,194,304 B
    unsigned short* g_ = (unsigned short*)(ws + 4194304);       //  1,048,576 B
    unsigned short* h_ = (unsigned short*)(ws + 5242880);       //  4,194,304 B
    unsigned short* o_ = (unsigned short*)(ws + 9437184);       // 16,777,216 B
    unsigned short* Wc = (unsigned short*)(ws + 26214400);      //     98,304 B
    unsigned short* Wv = (unsigned short*)(ws + 26312704);      //     65,536 B

    k_prep<<<192, 256, 0, stream>>>(wf, wg, wh, wv, Wc, Wv);
    k_conv_fgh<<<1024, 256, 0, stream>>>(x, Wc, bf, bg, bh, f_, g_, h_);
    k_attn<<<1024, 256, 0, stream>>>(f_, g_, h_, o_);
    k_out<<<1024, 256, 0, stream>>>(o_, Wv, bv, x, gamma, out);
}

// Round 7
// 211.147 us; speedup vs baseline: 1.0691x; 1.0691x over previous
//
#include <hip/hip_runtime.h>
#include <hip/hip_bf16.h>
#include <stdint.h>

#define B_N   16
#define C_N   256
#define W_N   64
#define HW_N  4096
#define CK_N  32      // f,g channels
#define CH_N  128     // h channels
#define HWP_N 1024    // pooled spatial
#define MR_N  192     // CK+CK+CH rows in fused conv weight

typedef __attribute__((ext_vector_type(8))) short short8;
typedef __attribute__((ext_vector_type(4))) short short4v;
typedef __attribute__((ext_vector_type(4))) float f32x4;

#define MFMA(a, b, c) __builtin_amdgcn_mfma_f32_16x16x32_bf16((a), (b), (c), 0, 0, 0)

// K=16 bf16 MFMA: A,B = 4 bf16 (2 VGPRs); C/D row=quad*4+r, col=l15
__device__ __forceinline__ f32x4 MFMA16B(short4v a, short4v b, f32x4 c) {
#if __has_builtin(__builtin_amdgcn_mfma_f32_16x16x16bf16_1k)
    return __builtin_amdgcn_mfma_f32_16x16x16bf16_1k(a, b, c, 0, 0, 0);
#else
    asm("v_mfma_f32_16x16x16_bf16 %0, %1, %2, %0" : "+v"(c) : "v"(a), "v"(b));
    return c;
#endif
}

__device__ __forceinline__ unsigned short f2bf(float f) {
    union { float f; unsigned u; } v; v.f = f;
    unsigned r = v.u + 0x7FFFu + ((v.u >> 16) & 1u);   // RNE
    return (unsigned short)(r >> 16);
}
// round-half-up bf16 pair pack: 3 VALU ops (add, add, v_perm)
__device__ __forceinline__ unsigned packrn(float lo, float hi) {
    unsigned a = __float_as_uint(lo) + 0x8000u;
    unsigned b = __float_as_uint(hi) + 0x8000u;
    return __builtin_amdgcn_perm(b, a, 0x07060302);  // (a>>16)|(b&0xFFFF0000)
}
__device__ __forceinline__ short8 ld8(const void* p) {
    return *reinterpret_cast<const short8*>(p);
}

// ---------------- kernel 0: cast weights to bf16 ----------------
__global__ __launch_bounds__(256) void k_prep(
    const float* __restrict__ wf, const float* __restrict__ wg,
    const float* __restrict__ wh, const float* __restrict__ wv,
    unsigned short* __restrict__ Wc, unsigned short* __restrict__ Wv)
{
    int i = blockIdx.x * 256 + threadIdx.x;
    if (i < MR_N * C_N) {
        int r = i / C_N, c = i % C_N;
        float v = (r < 32) ? wf[r * C_N + c]
                : (r < 64) ? wg[(r - 32) * C_N + c]
                           : wh[(r - 64) * C_N + c];
        Wc[i] = f2bf(v);
    }
    if (i < C_N * CH_N) Wv[i] = f2bf(wv[i]);
}

// ---------------- kernel 1: fused conv1x1 (f,g,h) + 2x2 maxpool ----------------
// f_/g_/h_ all bf16.
__global__ __launch_bounds__(256) void k_conv_fgh(
    const float* __restrict__ x, const unsigned short* __restrict__ Wc,
    const float* __restrict__ bfp, const float* __restrict__ bgp, const float* __restrict__ bhp,
    unsigned short* __restrict__ f_, unsigned short* __restrict__ g_, unsigned short* __restrict__ h_)
{
    __shared__ __align__(16) unsigned char lds[64 * 512];
    const int T = threadIdx.x;
    const int lane = T & 63, wid = T >> 6;
    const int blk = blockIdx.x;
    const int b = blk >> 6;
    const int seg = blk & 63;
    const int rp = seg >> 1;     // pooled row 0..31
    const int half = seg & 1;    // which 32-wide half of the row pair
    const float* xb = x + (size_t)b * C_N * HW_N;

    // stage x -> LDS bf16 (transpose to [px][ch] with chunk-XOR swizzle)
    #pragma unroll
    for (int i = 0; i < 8; ++i) {
        int task = i * 256 + T;        // 0..2047 = 16 px-quads x 128 ch-pairs
        int pq = task & 15;
        int cp = task >> 4;            // channel pair 0..127
        int px0 = pq * 4;
        int row = 2 * rp + (px0 >> 5);
        int wcol = half * 32 + (px0 & 31);
        const float4 v0 = *reinterpret_cast<const float4*>(xb + (size_t)(2 * cp) * HW_N + row * W_N + wcol);
        const float4 v1 = *reinterpret_cast<const float4*>(xb + (size_t)(2 * cp + 1) * HW_N + row * W_N + wcol);
        float vlo[4] = {v0.x, v0.y, v0.z, v0.w};
        float vhi[4] = {v1.x, v1.y, v1.z, v1.w};
        int kc = cp >> 2, co = cp & 3;
        #pragma unroll
        for (int j = 0; j < 4; ++j) {
            int px = px0 + j;
            *reinterpret_cast<unsigned*>(lds + px * 512 + ((kc ^ (px & 31)) << 4) + co * 4)
                = packrn(vlo[j], vhi[j]);
        }
    }
    __syncthreads();

    const int l15 = lane & 15, quad = lane >> 4;
    f32x4 acc[3][4];
    #pragma unroll
    for (int mt = 0; mt < 3; ++mt)
        #pragma unroll
        for (int nt = 0; nt < 4; ++nt)
            acc[mt][nt] = f32x4{0.f, 0.f, 0.f, 0.f};

    const int m0base = wid * 48;
    for (int k0 = 0; k0 < 256; k0 += 32) {
        short8 afr[3];
        #pragma unroll
        for (int mt = 0; mt < 3; ++mt)
            afr[mt] = ld8(Wc + (size_t)(m0base + mt * 16 + l15) * C_N + k0 + quad * 8);
        #pragma unroll
        for (int nt = 0; nt < 4; ++nt) {
            int px = nt * 16 + l15;
            int kc = (k0 >> 3) + quad;
            short8 bfr = ld8(lds + px * 512 + ((kc ^ (px & 31)) << 4));
            #pragma unroll
            for (int mt = 0; mt < 3; ++mt)
                acc[mt][nt] = MFMA(afr[mt], bfr, acc[mt][nt]);
        }
    }

    // epilogue: bias, pool, scatter to f/g/h
    #pragma unroll
    for (int mt = 0; mt < 3; ++mt) {
        int mbase = m0base + mt * 16;
        int mrow0 = mbase + quad * 4;
        float bias[4];
        #pragma unroll
        for (int r = 0; r < 4; ++r) {
            int m = mrow0 + r;
            bias[r] = (m < 32) ? bfp[m] : (m < 64) ? bgp[m - 32] : bhp[m - 64];
        }
        if (mbase < 32) {
            #pragma unroll
            for (int nt = 0; nt < 4; ++nt) {
                int px = nt * 16 + l15;
                int p = (2 * rp + (px >> 5)) * W_N + half * 32 + (px & 31);
                uint2 u;
                u.x = packrn(acc[mt][nt][0] + bias[0], acc[mt][nt][1] + bias[1]);
                u.y = packrn(acc[mt][nt][2] + bias[2], acc[mt][nt][3] + bias[3]);
                *reinterpret_cast<uint2*>(f_ + ((size_t)b * HW_N + p) * CK_N + mrow0) = u;
            }
        } else if (mbase < 64) {
            int gc0 = mrow0 - 32;
            #pragma unroll
            for (int nt = 0; nt < 2; ++nt) {
                float pv[4];
                #pragma unroll
                for (int r = 0; r < 4; ++r) {
                    float m1 = fmaxf(acc[mt][nt][r], acc[mt][nt + 2][r]);
                    pv[r] = fmaxf(m1, __shfl_xor(m1, 1)) + bias[r];
                }
                if ((lane & 1) == 0) {
                    int kp = rp * 32 + half * 16 + ((nt * 16 + l15) >> 1);
                    uint2 u;
                    u.x = packrn(pv[0], pv[1]);
                    u.y = packrn(pv[2], pv[3]);
                    *reinterpret_cast<uint2*>(g_ + ((size_t)b * HWP_N + kp) * CK_N + gc0) = u;
                }
            }
        } else {
            int hc0 = mrow0 - 64;
            #pragma unroll
            for (int nt = 0; nt < 2; ++nt) {
                float pv[4];
                #pragma unroll
                for (int r = 0; r < 4; ++r) {
                    float m1 = fmaxf(acc[mt][nt][r], acc[mt][nt + 2][r]);
                    pv[r] = fmaxf(m1, __shfl_xor(m1, 1)) + bias[r];
                }
                #pragma unroll
                for (int r = 0; r < 4; ++r) {
                    int lo = (int)(packrn(pv[r], pv[r]) & 0xFFFFu);  // bf16 bits
                    int hi = __shfl_down(lo, 2);
                    if ((lane & 3) == 0) {
                        int kp2 = rp * 32 + half * 16 + nt * 8 + (l15 >> 1);
                        *reinterpret_cast<unsigned*>(
                            h_ + ((size_t)b * CH_N + hc0 + r) * HWP_N + kp2)
                            = (unsigned)lo | ((unsigned)hi << 16);
                    }
                }
            }
        }
    }
}

// ---------------- kernel 2: fused attention ----------------
// 16 queries/wave, 4 waves/block (64 q), grid 1024 -> 4 waves/SIMD.
// Single pass, fixed logit shift (no row max): p = 2^(s*log2e - 28.854).
// V (bf16) staged per 64-key chunk in LDS [128ch][136B] (0-conflict pattern);
// P reg->reg into K=16 bf16 PV MFMA. No cross-wave combine.
__global__ __launch_bounds__(256, 4) void k_attn(
    const unsigned short* __restrict__ f_, const unsigned short* __restrict__ g_,
    const unsigned short* __restrict__ h_, unsigned short* __restrict__ o_)
{
    __shared__ __align__(16) unsigned char Vl[128 * 136];
    const int T = threadIdx.x;
    const int lane = T & 63, wid = T >> 6;
    const int l15 = lane & 15, quad = lane >> 4;

    const int blk = blockIdx.x;      // 1024 = 16 b x 64 qtiles(64q)
    const int b = blk >> 6;
    const int q0w = (blk & 63) * 64 + wid * 16;
    const unsigned short* fb = f_ + (size_t)b * HW_N * CK_N;
    const unsigned short* gb = g_ + (size_t)b * HWP_N * CK_N;
    const unsigned short* hb = h_ + (size_t)b * CH_N * HWP_N;

    short8 ffr = ld8(fb + (size_t)(q0w + l15) * CK_N + quad * 8);

    const f32x4 zf = {0.f, 0.f, 0.f, 0.f};
    f32x4 oacc[8];   // [ct]; D row = ch(quad*4+r), col = query(l15)
    #pragma unroll
    for (int ct = 0; ct < 8; ++ct)
        oacc[ct] = f32x4{0.f, 0.f, 0.f, 0.f};
    float lsum = 0.f;

    // staging coords: ch rows sch+32i (i<4), 16B key-chunk skq (0-conflict, r5-verified)
    const int sch = T >> 3, skq = T & 7;
    uint4 vpre[4];
    #pragma unroll
    for (int i = 0; i < 4; ++i)
        vpre[i] = *reinterpret_cast<const uint4*>(hb + (size_t)(sch + i * 32) * HWP_N + skq * 8);
    short8 gcur[4];
    #pragma unroll
    for (int kt = 0; kt < 4; ++kt)
        gcur[kt] = ld8(gb + (size_t)(kt * 16 + l15) * CK_N + quad * 8);

    for (int c = 0; c < 16; ++c) {
        const int key0 = c * 64;
        __syncthreads();   // previous chunk's V reads done
        #pragma unroll
        for (int i = 0; i < 4; ++i) {
            unsigned char* dst = Vl + (sch + i * 32) * 136 + skq * 16;
            *reinterpret_cast<uint2*>(dst)     = uint2{vpre[i].x, vpre[i].y};
            *reinterpret_cast<uint2*>(dst + 8) = uint2{vpre[i].z, vpre[i].w};
        }
        if (c < 15) {
            #pragma unroll
            for (int i = 0; i < 4; ++i)
                vpre[i] = *reinterpret_cast<const uint4*>(
                    hb + (size_t)(sch + i * 32) * HWP_N + key0 + 64 + skq * 8);
        }
        __syncthreads();   // V writes visible

        // QK: sp row=key(quad*4+r), col=q(l15)
        f32x4 sp[4];
        #pragma unroll
        for (int kt = 0; kt < 4; ++kt)
            sp[kt] = MFMA(gcur[kt], ffr, zf);
        if (c < 15) {
            #pragma unroll
            for (int kt = 0; kt < 4; ++kt)
                gcur[kt] = ld8(gb + (size_t)(key0 + 64 + kt * 16 + l15) * CK_N + quad * 8);
        }

        // exp2 fixed shift, accumulate denom, build bf16 B-frags in regs
        short4v pf[4];
        float lw = 0.f;
        #pragma unroll
        for (int kt = 0; kt < 4; ++kt) {
            float p0 = __builtin_amdgcn_exp2f(sp[kt][0] * 1.44269504f - 28.85390082f);
            float p1 = __builtin_amdgcn_exp2f(sp[kt][1] * 1.44269504f - 28.85390082f);
            float p2 = __builtin_amdgcn_exp2f(sp[kt][2] * 1.44269504f - 28.85390082f);
            float p3 = __builtin_amdgcn_exp2f(sp[kt][3] * 1.44269504f - 28.85390082f);
            lw += (p0 + p1) + (p2 + p3);
            uint2 u{packrn(p0, p1), packrn(p2, p3)};
            pf[kt] = __builtin_bit_cast(short4v, u);
        }
        lsum += lw;

        // PV: A = V[ch][4 keys] (b64 LDS, conflict-free), B = pf (regs), K=16
        const int vbase = l15 * 136 + quad * 8;
        #pragma unroll
        for (int ct = 0; ct < 8; ++ct) {
            #pragma unroll
            for (int kt = 0; kt < 4; ++kt) {
                short4v afr = *reinterpret_cast<const short4v*>(Vl + vbase + ct * 2176 + kt * 32);
                oacc[ct] = MFMA16B(afr, pf[kt], oacc[ct]);
            }
        }
    }

    // reduce denominator across quads (lanes share query = l15), scale, store
    lsum += __shfl_xor(lsum, 16); lsum += __shfl_xor(lsum, 32);
    const float rl = 1.f / lsum;
    unsigned short* ob = o_ + (size_t)b * HW_N * CH_N;
    const int q = q0w + l15;
    #pragma unroll
    for (int ct = 0; ct < 8; ++ct) {
        uint2 u;
        u.x = packrn(oacc[ct][0] * rl, oacc[ct][1] * rl);
        u.y = packrn(oacc[ct][2] * rl, oacc[ct][3] * rl);
        *reinterpret_cast<uint2*>(ob + (size_t)q * CH_N + ct * 16 + quad * 4) = u;
    }
}

// ---------------- kernel 3: final conv1x1 + gamma + residual ----------------
__global__ __launch_bounds__(256) void k_out(
    const unsigned short* __restrict__ o_, const unsigned short* __restrict__ Wv,
    const float* __restrict__ bv, const float* __restrict__ x,
    const float* __restrict__ gamma_p, float* __restrict__ out)
{
    __shared__ __align__(16) unsigned char lds[64 * 272];
    const int T = threadIdx.x;
    const int lane = T & 63, wid = T >> 6;
    const int blk = blockIdx.x;
    const int b = blk >> 6;
    const int p0 = (blk & 63) * 64;
    const unsigned short* ob = o_ + ((size_t)b * HW_N + p0) * CH_N;

    #pragma unroll
    for (int i = 0; i < 4; ++i) {      // stage o tile: 64px x 128ch, padded rows
        int task = i * 256 + T;
        int p = task >> 4, kc = task & 15;
        short8 v = ld8(ob + p * CH_N + kc * 8);
        *reinterpret_cast<short8*>(lds + p * 272 + kc * 16) = v;
    }
    __syncthreads();

    const int l15 = lane & 15, quad = lane >> 4;
    f32x4 acc[4][4];   // acc[oc-tile][px-tile]; D row=px(quad*4+r), col=oc(l15)
    #pragma unroll
    for (int mt = 0; mt < 4; ++mt)
        #pragma unroll
        for (int nt = 0; nt < 4; ++nt)
            acc[mt][nt] = f32x4{0.f, 0.f, 0.f, 0.f};

    const int m0b = wid * 64;
    #pragma unroll
    for (int k0 = 0; k0 < 128; k0 += 32) {
        short8 bfr[4];   // o-tile fragments, m = px (A operand)
        #pragma unroll
        for (int nt = 0; nt < 4; ++nt)
            bfr[nt] = ld8(lds + (nt * 16 + l15) * 272 + k0 * 2 + quad * 16);
        #pragma unroll
        for (int mt = 0; mt < 4; ++mt) {
            short8 afr = ld8(Wv + (size_t)(m0b + mt * 16 + l15) * CH_N + k0 + quad * 8);
            #pragma unroll
            for (int nt = 0; nt < 4; ++nt)
                acc[mt][nt] = MFMA(bfr[nt], afr, acc[mt][nt]);  // A=o(px), B=Wv(oc)
        }
    }

    const float gamma = *gamma_p;
    const float* xb = x + (size_t)b * C_N * HW_N;
    float* outb = out + (size_t)b * C_N * HW_N;
    #pragma unroll
    for (int mt = 0; mt < 4; ++mt) {
        int oc = m0b + mt * 16 + l15;
        float bvv = bv[oc];
        #pragma unroll
        for (int nt = 0; nt < 4; ++nt) {
            size_t base = (size_t)oc * HW_N + p0 + nt * 16 + quad * 4;
            float4 xv = *reinterpret_cast<const float4*>(xb + base);
            float4 ov;
            ov.x = gamma * (acc[mt][nt][0] + bvv) + xv.x;
            ov.y = gamma * (acc[mt][nt][1] + bvv) + xv.y;
            ov.z = gamma * (acc[mt][nt][2] + bvv) + xv.z;
            ov.w = gamma * (acc[mt][nt][3] + bvv) + xv.w;
            *reinterpret_cast<float4*>(outb + base) = ov;
        }
    }
}

// ---------------- launch ----------------
extern "C" void kernel_launch(void* const* d_in, const int* in_sizes, int n_in,
                              void* d_out, int out_size, void* d_ws, size_t ws_size,
                              hipStream_t stream) {
    const float* x     = (const float*)d_in[0];
    const float* wf    = (const float*)d_in[1];
    const float* bf    = (const float*)d_in[2];
    const float* wg    = (const float*)d_in[3];
    const float* bg    = (const float*)d_in[4];
    const float* wh    = (const float*)d_in[5];
    const float* bh    = (const float*)d_in[6];
    const float* wv    = (const float*)d_in[7];
    const float* bv    = (const float*)d_in[8];
    const float* gamma = (const float*)d_in[9];
    float* out = (float*)d_out;
    char* ws = (char*)d_ws;

    unsigned short* f_ = (unsigned short*)(ws);                 //  4,194,304 B
    unsigned short* g_ = (unsigned short*)(ws + 4194304);       //  1,048,576 B
    unsigned short* h_ = (unsigned short*)(ws + 5242880);       //  4,194,304 B
    unsigned short* o_ = (unsigned short*)(ws + 9437184);       // 16,777,216 B
    unsigned short* Wc = (unsigned short*)(ws + 26214400);      //     98,304 B
    unsigned short* Wv = (unsigned short*)(ws + 26312704);      //     65,536 B

    k_prep<<<192, 256, 0, stream>>>(wf, wg, wh, wv, Wc, Wv);
    k_conv_fgh<<<1024, 256, 0, stream>>>(x, Wc, bf, bg, bh, f_, g_, h_);
    k_attn<<<1024, 256, 0, stream>>>(f_, g_, h_, o_);
    k_out<<<1024, 256, 0, stream>>>(o_, Wv, bv, x, gamma, out);
}

// Round 8
// 207.831 us; speedup vs baseline: 1.0862x; 1.0160x over previous
//
#include <hip/hip_runtime.h>
#include <hip/hip_bf16.h>
#include <stdint.h>

#define B_N   16
#define C_N   256
#define W_N   64
#define HW_N  4096
#define CK_N  32      // f,g channels
#define CH_N  128     // h channels
#define HWP_N 1024    // pooled spatial
#define MR_N  192     // CK+CK+CH rows in fused conv weight

typedef __attribute__((ext_vector_type(8))) short short8;
typedef __attribute__((ext_vector_type(4))) short short4v;
typedef __attribute__((ext_vector_type(4))) float f32x4;

#define MFMA(a, b, c) __builtin_amdgcn_mfma_f32_16x16x32_bf16((a), (b), (c), 0, 0, 0)

// K=16 bf16 MFMA: A,B = 4 bf16 (2 VGPRs); C/D row=quad*4+r, col=l15
__device__ __forceinline__ f32x4 MFMA16B(short4v a, short4v b, f32x4 c) {
#if __has_builtin(__builtin_amdgcn_mfma_f32_16x16x16bf16_1k)
    return __builtin_amdgcn_mfma_f32_16x16x16bf16_1k(a, b, c, 0, 0, 0);
#else
    asm("v_mfma_f32_16x16x16_bf16 %0, %1, %2, %0" : "+v"(c) : "v"(a), "v"(b));
    return c;
#endif
}

__device__ __forceinline__ unsigned short f2bf(float f) {
    union { float f; unsigned u; } v; v.f = f;
    unsigned r = v.u + 0x7FFFu + ((v.u >> 16) & 1u);   // RNE
    return (unsigned short)(r >> 16);
}
// round-half-up bf16 pair pack: 3 VALU ops (add, add, v_perm)
__device__ __forceinline__ unsigned packrn(float lo, float hi) {
    unsigned a = __float_as_uint(lo) + 0x8000u;
    unsigned b = __float_as_uint(hi) + 0x8000u;
    return __builtin_amdgcn_perm(b, a, 0x07060302);  // (a>>16)|(b&0xFFFF0000)
}
__device__ __forceinline__ short8 ld8(const void* p) {
    return *reinterpret_cast<const short8*>(p);
}

// ---------------- kernel 0: cast weights to bf16 ----------------
__global__ __launch_bounds__(256) void k_prep(
    const float* __restrict__ wf, const float* __restrict__ wg,
    const float* __restrict__ wh, const float* __restrict__ wv,
    unsigned short* __restrict__ Wc, unsigned short* __restrict__ Wv)
{
    int i = blockIdx.x * 256 + threadIdx.x;
    if (i < MR_N * C_N) {
        int r = i / C_N, c = i % C_N;
        float v = (r < 32) ? wf[r * C_N + c]
                : (r < 64) ? wg[(r - 32) * C_N + c]
                           : wh[(r - 64) * C_N + c];
        Wc[i] = f2bf(v);
    }
    if (i < C_N * CH_N) Wv[i] = f2bf(wv[i]);
}

// ---------------- kernel 1: fused conv1x1 (f,g,h) + 2x2 maxpool ----------------
// f_/g_/h_ all bf16.
__global__ __launch_bounds__(256) void k_conv_fgh(
    const float* __restrict__ x, const unsigned short* __restrict__ Wc,
    const float* __restrict__ bfp, const float* __restrict__ bgp, const float* __restrict__ bhp,
    unsigned short* __restrict__ f_, unsigned short* __restrict__ g_, unsigned short* __restrict__ h_)
{
    __shared__ __align__(16) unsigned char lds[64 * 512];
    const int T = threadIdx.x;
    const int lane = T & 63, wid = T >> 6;
    const int blk = blockIdx.x;
    const int b = blk >> 6;
    const int seg = blk & 63;
    const int rp = seg >> 1;     // pooled row 0..31
    const int half = seg & 1;    // which 32-wide half of the row pair
    const float* xb = x + (size_t)b * C_N * HW_N;

    // stage x -> LDS bf16 (transpose to [px][ch] with chunk-XOR swizzle)
    #pragma unroll
    for (int i = 0; i < 8; ++i) {
        int task = i * 256 + T;        // 0..2047 = 16 px-quads x 128 ch-pairs
        int pq = task & 15;
        int cp = task >> 4;            // channel pair 0..127
        int px0 = pq * 4;
        int row = 2 * rp + (px0 >> 5);
        int wcol = half * 32 + (px0 & 31);
        const float4 v0 = *reinterpret_cast<const float4*>(xb + (size_t)(2 * cp) * HW_N + row * W_N + wcol);
        const float4 v1 = *reinterpret_cast<const float4*>(xb + (size_t)(2 * cp + 1) * HW_N + row * W_N + wcol);
        float vlo[4] = {v0.x, v0.y, v0.z, v0.w};
        float vhi[4] = {v1.x, v1.y, v1.z, v1.w};
        int kc = cp >> 2, co = cp & 3;
        #pragma unroll
        for (int j = 0; j < 4; ++j) {
            int px = px0 + j;
            *reinterpret_cast<unsigned*>(lds + px * 512 + ((kc ^ (px & 31)) << 4) + co * 4)
                = packrn(vlo[j], vhi[j]);
        }
    }
    __syncthreads();

    const int l15 = lane & 15, quad = lane >> 4;
    f32x4 acc[3][4];
    #pragma unroll
    for (int mt = 0; mt < 3; ++mt)
        #pragma unroll
        for (int nt = 0; nt < 4; ++nt)
            acc[mt][nt] = f32x4{0.f, 0.f, 0.f, 0.f};

    const int m0base = wid * 48;
    for (int k0 = 0; k0 < 256; k0 += 32) {
        short8 afr[3];
        #pragma unroll
        for (int mt = 0; mt < 3; ++mt)
            afr[mt] = ld8(Wc + (size_t)(m0base + mt * 16 + l15) * C_N + k0 + quad * 8);
        #pragma unroll
        for (int nt = 0; nt < 4; ++nt) {
            int px = nt * 16 + l15;
            int kc = (k0 >> 3) + quad;
            short8 bfr = ld8(lds + px * 512 + ((kc ^ (px & 31)) << 4));
            #pragma unroll
            for (int mt = 0; mt < 3; ++mt)
                acc[mt][nt] = MFMA(afr[mt], bfr, acc[mt][nt]);
        }
    }

    // epilogue: bias, pool, scatter to f/g/h
    #pragma unroll
    for (int mt = 0; mt < 3; ++mt) {
        int mbase = m0base + mt * 16;
        int mrow0 = mbase + quad * 4;
        float bias[4];
        #pragma unroll
        for (int r = 0; r < 4; ++r) {
            int m = mrow0 + r;
            bias[r] = (m < 32) ? bfp[m] : (m < 64) ? bgp[m - 32] : bhp[m - 64];
        }
        if (mbase < 32) {
            #pragma unroll
            for (int nt = 0; nt < 4; ++nt) {
                int px = nt * 16 + l15;
                int p = (2 * rp + (px >> 5)) * W_N + half * 32 + (px & 31);
                uint2 u;
                u.x = packrn(acc[mt][nt][0] + bias[0], acc[mt][nt][1] + bias[1]);
                u.y = packrn(acc[mt][nt][2] + bias[2], acc[mt][nt][3] + bias[3]);
                *reinterpret_cast<uint2*>(f_ + ((size_t)b * HW_N + p) * CK_N + mrow0) = u;
            }
        } else if (mbase < 64) {
            int gc0 = mrow0 - 32;
            #pragma unroll
            for (int nt = 0; nt < 2; ++nt) {
                float pv[4];
                #pragma unroll
                for (int r = 0; r < 4; ++r) {
                    float m1 = fmaxf(acc[mt][nt][r], acc[mt][nt + 2][r]);
                    pv[r] = fmaxf(m1, __shfl_xor(m1, 1)) + bias[r];
                }
                if ((lane & 1) == 0) {
                    int kp = rp * 32 + half * 16 + ((nt * 16 + l15) >> 1);
                    uint2 u;
                    u.x = packrn(pv[0], pv[1]);
                    u.y = packrn(pv[2], pv[3]);
                    *reinterpret_cast<uint2*>(g_ + ((size_t)b * HWP_N + kp) * CK_N + gc0) = u;
                }
            }
        } else {
            int hc0 = mrow0 - 64;
            #pragma unroll
            for (int nt = 0; nt < 2; ++nt) {
                float pv[4];
                #pragma unroll
                for (int r = 0; r < 4; ++r) {
                    float m1 = fmaxf(acc[mt][nt][r], acc[mt][nt + 2][r]);
                    pv[r] = fmaxf(m1, __shfl_xor(m1, 1)) + bias[r];
                }
                #pragma unroll
                for (int r = 0; r < 4; ++r) {
                    int lo = (int)(packrn(pv[r], pv[r]) & 0xFFFFu);  // bf16 bits
                    int hi = __shfl_down(lo, 2);
                    if ((lane & 3) == 0) {
                        int kp2 = rp * 32 + half * 16 + nt * 8 + (l15 >> 1);
                        *reinterpret_cast<unsigned*>(
                            h_ + ((size_t)b * CH_N + hc0 + r) * HWP_N + kp2)
                            = (unsigned)lo | ((unsigned)hi << 16);
                    }
                }
            }
        }
    }
}

// ---------------- kernel 2: fused attention ----------------
// 16 queries/wave, 4 waves/block, grid 1024 -> 4 blocks/CU. Fixed-shift softmax.
// V double-buffered in LDS (2 x [128ch][136B], 0-conflict b64 reads):
// ONE barrier per 64-key chunk; chunk c+1 global loads overlap chunk c compute.
__global__ __launch_bounds__(256, 4) void k_attn(
    const unsigned short* __restrict__ f_, const unsigned short* __restrict__ g_,
    const unsigned short* __restrict__ h_, unsigned short* __restrict__ o_)
{
    __shared__ __align__(16) unsigned char Vl[2 * 17408];
    const int T = threadIdx.x;
    const int lane = T & 63, wid = T >> 6;
    const int l15 = lane & 15, quad = lane >> 4;

    const int blk = blockIdx.x;      // 1024 = 16 b x 64 qtiles(64q)
    const int b = blk >> 6;
    const int q0w = (blk & 63) * 64 + wid * 16;
    const unsigned short* fb = f_ + (size_t)b * HW_N * CK_N;
    const unsigned short* gb = g_ + (size_t)b * HWP_N * CK_N;
    const unsigned short* hb = h_ + (size_t)b * CH_N * HWP_N;

    short8 ffr = ld8(fb + (size_t)(q0w + l15) * CK_N + quad * 8);

    const f32x4 zf = {0.f, 0.f, 0.f, 0.f};
    f32x4 oacc[8];   // [ct]; D row = ch(quad*4+r), col = query(l15)
    #pragma unroll
    for (int ct = 0; ct < 8; ++ct)
        oacc[ct] = f32x4{0.f, 0.f, 0.f, 0.f};
    float lsum = 0.f;

    // staging coords: ch rows sch+32i (i<4), 16B key-chunk skq (0-conflict)
    const int sch = T >> 3, skq = T & 7;
    uint4 vpre[4];
    #pragma unroll
    for (int i = 0; i < 4; ++i)
        vpre[i] = *reinterpret_cast<const uint4*>(hb + (size_t)(sch + i * 32) * HWP_N + skq * 8);
    short8 gcur[4];
    #pragma unroll
    for (int kt = 0; kt < 4; ++kt)
        gcur[kt] = ld8(gb + (size_t)(kt * 16 + l15) * CK_N + quad * 8);

    for (int c = 0; c < 16; ++c) {
        unsigned char* buf = Vl + (c & 1) * 17408;
        // write chunk c's V (WAR on this buffer was cleared by iter c-1's barrier)
        #pragma unroll
        for (int i = 0; i < 4; ++i) {
            unsigned char* dst = buf + (sch + i * 32) * 136 + skq * 16;
            *reinterpret_cast<uint2*>(dst)     = uint2{vpre[i].x, vpre[i].y};
            *reinterpret_cast<uint2*>(dst + 8) = uint2{vpre[i].z, vpre[i].w};
        }
        // issue chunk c+1 global loads (land during chunk c compute)
        if (c < 15) {
            #pragma unroll
            for (int i = 0; i < 4; ++i)
                vpre[i] = *reinterpret_cast<const uint4*>(
                    hb + (size_t)(sch + i * 32) * HWP_N + (c + 1) * 64 + skq * 8);
        }
        __syncthreads();   // buf writes visible; single barrier per chunk

        // QK: sp row=key(quad*4+r), col=q(l15)
        f32x4 sp[4];
        #pragma unroll
        for (int kt = 0; kt < 4; ++kt)
            sp[kt] = MFMA(gcur[kt], ffr, zf);
        if (c < 15) {
            #pragma unroll
            for (int kt = 0; kt < 4; ++kt)
                gcur[kt] = ld8(gb + (size_t)((c + 1) * 64 + kt * 16 + l15) * CK_N + quad * 8);
        }

        // exp2 fixed shift, accumulate denom, build bf16 B-frags in regs
        short4v pf[4];
        float lw = 0.f;
        #pragma unroll
        for (int kt = 0; kt < 4; ++kt) {
            float p0 = __builtin_amdgcn_exp2f(sp[kt][0] * 1.44269504f - 28.85390082f);
            float p1 = __builtin_amdgcn_exp2f(sp[kt][1] * 1.44269504f - 28.85390082f);
            float p2 = __builtin_amdgcn_exp2f(sp[kt][2] * 1.44269504f - 28.85390082f);
            float p3 = __builtin_amdgcn_exp2f(sp[kt][3] * 1.44269504f - 28.85390082f);
            lw += (p0 + p1) + (p2 + p3);
            uint2 u{packrn(p0, p1), packrn(p2, p3)};
            pf[kt] = __builtin_bit_cast(short4v, u);
        }
        lsum += lw;

        // PV: A = V[ch][4 keys] (b64 LDS, conflict-free), B = pf (regs), K=16
        const int vbase = l15 * 136 + quad * 8;
        #pragma unroll
        for (int ct = 0; ct < 8; ++ct) {
            #pragma unroll
            for (int kt = 0; kt < 4; ++kt) {
                short4v afr = *reinterpret_cast<const short4v*>(buf + vbase + ct * 2176 + kt * 32);
                oacc[ct] = MFMA16B(afr, pf[kt], oacc[ct]);
            }
        }
    }

    // reduce denominator across quads (lanes share query = l15), scale, store
    lsum += __shfl_xor(lsum, 16); lsum += __shfl_xor(lsum, 32);
    const float rl = 1.f / lsum;
    unsigned short* ob = o_ + (size_t)b * HW_N * CH_N;
    const int q = q0w + l15;
    #pragma unroll
    for (int ct = 0; ct < 8; ++ct) {
        uint2 u;
        u.x = packrn(oacc[ct][0] * rl, oacc[ct][1] * rl);
        u.y = packrn(oacc[ct][2] * rl, oacc[ct][3] * rl);
        *reinterpret_cast<uint2*>(ob + (size_t)q * CH_N + ct * 16 + quad * 4) = u;
    }
}

// ---------------- kernel 3: final conv1x1 + gamma + residual ----------------
// No LDS, no barriers: each wave = independent 64px x 64oc task; o fragments
// read directly from global (o_ layout [px][128ch] IS the A-frag layout).
__global__ __launch_bounds__(256, 4) void k_out(
    const unsigned short* __restrict__ o_, const unsigned short* __restrict__ Wv,
    const float* __restrict__ bv, const float* __restrict__ x,
    const float* __restrict__ gamma_p, float* __restrict__ out)
{
    const int T = threadIdx.x;
    const int lane = T & 63, wid = T >> 6;
    const int l15 = lane & 15, quad = lane >> 4;
    const int w = blockIdx.x * 4 + wid;   // 4096 wave tasks
    const int b = w >> 8;
    const int rem = w & 255;              // 4 oc-tiles x 64 px-tiles
    const int oc0 = (rem >> 6) * 64;
    const int px0 = (rem & 63) * 64;
    const unsigned short* ob = o_ + ((size_t)b * HW_N + px0) * CH_N;

    f32x4 acc[4][4];   // acc[mt][nt]; D row=px(quad*4+r), col=oc(l15)
    #pragma unroll
    for (int mt = 0; mt < 4; ++mt)
        #pragma unroll
        for (int nt = 0; nt < 4; ++nt)
            acc[mt][nt] = f32x4{0.f, 0.f, 0.f, 0.f};

    #pragma unroll
    for (int k0 = 0; k0 < 128; k0 += 32) {
        short8 bfr[4];   // o fragments (A operand, m = px), straight from global
        #pragma unroll
        for (int nt = 0; nt < 4; ++nt)
            bfr[nt] = ld8(ob + (size_t)(nt * 16 + l15) * CH_N + k0 + quad * 8);
        #pragma unroll
        for (int mt = 0; mt < 4; ++mt) {
            short8 afr = ld8(Wv + (size_t)(oc0 + mt * 16 + l15) * CH_N + k0 + quad * 8);
            #pragma unroll
            for (int nt = 0; nt < 4; ++nt)
                acc[mt][nt] = MFMA(bfr[nt], afr, acc[mt][nt]);  // A=o(px), B=Wv(oc)
        }
    }

    const float gamma = *gamma_p;
    const float* xb = x + (size_t)b * C_N * HW_N;
    float* outb = out + (size_t)b * C_N * HW_N;
    #pragma unroll
    for (int mt = 0; mt < 4; ++mt) {
        int oc = oc0 + mt * 16 + l15;
        float bvv = bv[oc];
        #pragma unroll
        for (int nt = 0; nt < 4; ++nt) {
            size_t base = (size_t)oc * HW_N + px0 + nt * 16 + quad * 4;
            float4 xv = *reinterpret_cast<const float4*>(xb + base);
            float4 ov;
            ov.x = gamma * (acc[mt][nt][0] + bvv) + xv.x;
            ov.y = gamma * (acc[mt][nt][1] + bvv) + xv.y;
            ov.z = gamma * (acc[mt][nt][2] + bvv) + xv.z;
            ov.w = gamma * (acc[mt][nt][3] + bvv) + xv.w;
            *reinterpret_cast<float4*>(outb + base) = ov;
        }
    }
}

// ---------------- launch ----------------
extern "C" void kernel_launch(void* const* d_in, const int* in_sizes, int n_in,
                              void* d_out, int out_size, void* d_ws, size_t ws_size,
                              hipStream_t stream) {
    const float* x     = (const float*)d_in[0];
    const float* wf    = (const float*)d_in[1];
    const float* bf    = (const float*)d_in[2];
    const float* wg    = (const float*)d_in[3];
    const float* bg    = (const float*)d_in[4];
    const float* wh    = (const float*)d_in[5];
    const float* bh    = (const float*)d_in[6];
    const float* wv    = (const float*)d_in[7];
    const float* bv    = (const float*)d_in[8];
    const float* gamma = (const float*)d_in[9];
    float* out = (float*)d_out;
    char* ws = (char*)d_ws;

    unsigned short* f_ = (unsigned short*)(ws);                 //  4,194,304 B
    unsigned short* g_ = (unsigned short*)(ws + 4194304);       //  1,048,576 B
    unsigned short* h_ = (unsigned short*)(ws + 5242880);       //  4,194,304 B
    unsigned short* o_ = (unsigned short*)(ws + 9437184);       // 16,777,216 B
    unsigned short* Wc = (unsigned short*)(ws + 26214400);      //     98,304 B
    unsigned short* Wv = (unsigned short*)(ws + 26312704);      //     65,536 B

    k_prep<<<192, 256, 0, stream>>>(wf, wg, wh, wv, Wc, Wv);
    k_conv_fgh<<<1024, 256, 0, stream>>>(x, Wc, bf, bg, bh, f_, g_, h_);
    k_attn<<<1024, 256, 0, stream>>>(f_, g_, h_, o_);
    k_out<<<1024, 256, 0, stream>>>(o_, Wv, bv, x, gamma, out);
}